// Round 5
// baseline (361.249 us; speedup 1.0000x reference)
//
#include <hip/hip_runtime.h>

// B=8, LQ=LK=2048, D=128, fp32 in/out: softmax(qk*scale) @ V.
// Flash attention, S^T/O^T orientation, 32x32x16 f16 MFMA.
// R5: 4-wave blocks with k-split-within-block (wave w owns keys w*512..+512),
//     barrier-free main loop, 2-barrier LDS epilogue (m-merge + O-sum).
//     8 waves/CU. prep fully coalesced via LDS transpose tiles.

typedef float          f32x4  __attribute__((ext_vector_type(4)));
typedef float          f32x16 __attribute__((ext_vector_type(16)));
typedef _Float16       h16x8  __attribute__((ext_vector_type(8)));
typedef unsigned int   u32x4  __attribute__((ext_vector_type(4)));
typedef unsigned short u16x4  __attribute__((ext_vector_type(4)));
typedef unsigned short u16x8  __attribute__((ext_vector_type(8)));

#define LOG2E 1.4426950408889634f

__device__ __forceinline__ float fast_exp2(float x) {
#if __has_builtin(__builtin_amdgcn_exp2f)
    return __builtin_amdgcn_exp2f(x);
#else
    return exp2f(x);
#endif
}

// ---------------- prep: Q/K/V -> fragment-major fp16, fully coalesced ----------------
// Layouts (frag-major, 16 B/lane, 1 KB/frag-row):
//  qhF/qlF/khF: fr = ((b*64+tile)*8+s): elem j = X[b][tile*32+(lane&31)][s*16+(lane>>5)*8+j]
//  vF:          fr = ((b*64+kc)*8+td*2+s2): elem j = V[b][kc*32+s2*16+(lane>>5)*8+j][td*32+(lane&31)]
#define TS 136   // LDS tile row stride (u16), 272 B: 16 B-aligned rows
__global__ __launch_bounds__(256)
void prep_all(const float* __restrict__ q, const float* __restrict__ k,
              const float* __restrict__ v,
              unsigned short* __restrict__ qhF, unsigned short* __restrict__ qlF,
              unsigned short* __restrict__ khF, unsigned short* __restrict__ vF) {
    __shared__ unsigned short hiT[32 * TS];
    __shared__ unsigned short loT[32 * TS];
    const int bid  = blockIdx.x;         // 0..1535
    const int kind = bid >> 9;           // 0=Q, 1=K, 2=V
    const int id   = bid & 511;          // b*64 + tile
    const int b    = id >> 6;
    const int tile = id & 63;
    const int tid  = threadIdx.x;
    const float* src = kind == 0 ? q : (kind == 1 ? k : v);

    // coalesced load 32x128 fp32 tile + convert
#pragma unroll
    for (int it = 0; it < 4; ++it) {
        int idx = it * 256 + tid;        // f32x4 idx 0..1023
        int row = idx >> 5;
        int c4  = idx & 31;
        f32x4 val = *(const f32x4*)(src + ((size_t)(b * 2048 + tile * 32 + row) * 128 + c4 * 4));
        u16x4 hi4, lo4;
#pragma unroll
        for (int j = 0; j < 4; ++j) {
            _Float16 hh = (_Float16)val[j];
            hi4[j] = __builtin_bit_cast(unsigned short, hh);
            _Float16 ll = (_Float16)(val[j] - (float)hh);
            lo4[j] = __builtin_bit_cast(unsigned short, ll);
        }
        *(u16x4*)&hiT[row * TS + c4 * 4] = hi4;
        if (kind == 0) *(u16x4*)&loT[row * TS + c4 * 4] = lo4;
    }
    __syncthreads();

    if (kind < 2) {                      // Q / K: aligned 16 B frag reads
#pragma unroll
        for (int e = 0; e < 2; ++e) {
            int fi   = e * 256 + tid;    // 0..511
            int lane = fi & 63;
            int s    = fi >> 6;
            int off  = (lane & 31) * TS + s * 16 + (lane >> 5) * 8;
            u16x8 hi8 = *(const u16x8*)&hiT[off];
            size_t o = ((size_t)(id * 8 + s) * 64 + lane) * 8;
            if (kind == 0) {
                u16x8 lo8 = *(const u16x8*)&loT[off];
                *(u16x8*)(qhF + o) = hi8;
                *(u16x8*)(qlF + o) = lo8;
            } else {
                *(u16x8*)(khF + o) = hi8;
            }
        }
    } else {                             // V: transposed frag gather
#pragma unroll
        for (int e = 0; e < 2; ++e) {
            int fi   = e * 256 + tid;
            int lane = fi & 63;
            int fr2  = fi >> 6;          // td*2+s2
            int td   = fr2 >> 1;
            int s2   = fr2 & 1;
            u16x8 o8;
#pragma unroll
            for (int j = 0; j < 8; ++j)
                o8[j] = hiT[(s2 * 16 + (lane >> 5) * 8 + j) * TS + td * 32 + (lane & 31)];
            *(u16x8*)(vF + ((size_t)(id * 8 + fr2) * 64 + lane) * 8) = o8;
        }
    }
}

// ---------------- flash attention main kernel ----------------
// LDS (bytes): loop: scb[4 waves][2 bufs][32*36 f32] = 36864
//              epilogue (aliased from 0): oex[4][32*132 f32] = 67584
//              mstat [4][32] f32 @67584, lstat [4][32] f32 @68096; total 68608
#define LDSZ  68608
#define MOFF  67584
#define LOFF  68096

__global__ __launch_bounds__(256, 2)
void flash_fwd(const unsigned short* __restrict__ qhF,
               const unsigned short* __restrict__ qlF,
               const unsigned short* __restrict__ khF,
               const unsigned short* __restrict__ vF,
               const float* __restrict__ scale_g,
               float* __restrict__ out) {
    __shared__ unsigned char smem[LDSZ];

    const int tid  = threadIdx.x;
    const int wave = tid >> 6;
    const int lane = tid & 63;
    const int q31  = lane & 31;
    const int h    = lane >> 5;

    const int bid = blockIdx.x;
    const int b   = bid & 7;             // batch <-> XCD affinity
    const int qt  = bid >> 3;            // 0..63

    float* scb   = (float*)(smem + wave * 9216);   // 2 x 1152 floats
    float* oex   = (float*)smem;
    float* mstat = (float*)(smem + MOFF);
    float* lstat = (float*)(smem + LOFF);

    // ---- resident Q fragments ----
    h16x8 qh[8], ql[8];
    {
        const u32x4* qp = (const u32x4*)qhF + ((size_t)(b * 64 + qt) * 8) * 64 + lane;
        const u32x4* lp = (const u32x4*)qlF + ((size_t)(b * 64 + qt) * 8) * 64 + lane;
#pragma unroll
        for (int s = 0; s < 8; ++s) {
            qh[s] = __builtin_bit_cast(h16x8, qp[s * 64]);
            ql[s] = __builtin_bit_cast(h16x8, lp[s * 64]);
        }
    }

    // wave's private 512-key range: 16 chunks of 32
    const int ck0 = b * 64 + wave * 16;
    const u32x4* khp = (const u32x4*)khF + ((size_t)ck0 * 8) * 64 + lane;
    const u32x4* vp  = (const u32x4*)vF  + ((size_t)ck0 * 8) * 64 + lane;

    const int kbase = wave * 512;
    int scrow[4];
#pragma unroll
    for (int j = 0; j < 4; ++j)
        scrow[j] = (b * 2048 + qt * 32 + j * 8 + (lane >> 3)) * 2048 + kbase + (lane & 7) * 4;

    f32x16 oacc[4];
#pragma unroll
    for (int t = 0; t < 4; ++t)
#pragma unroll
        for (int r = 0; r < 16; ++r) oacc[t][r] = 0.f;
    float m_run = -INFINITY, l_run = 0.f;

    h16x8 khr[2][8], vr[2][8];
    f32x4 scv[2][4];

    // ---- prologue ----
#pragma unroll
    for (int s = 0; s < 8; ++s) khr[0][s] = __builtin_bit_cast(h16x8, khp[s * 64]);
#pragma unroll
    for (int f = 0; f < 8; ++f) vr[0][f]  = __builtin_bit_cast(h16x8, vp[f * 64]);
#pragma unroll
    for (int j = 0; j < 4; ++j) scv[0][j] = *(const f32x4*)(scale_g + scrow[j]);
#pragma unroll
    for (int j = 0; j < 4; ++j) scv[1][j] = *(const f32x4*)(scale_g + scrow[j] + 32);
#pragma unroll
    for (int j = 0; j < 4; ++j)
        *(f32x4*)&scb[(j * 8 + (lane >> 3)) * 36 + (lane & 7) * 4] = scv[0][j];

    for (int kc2 = 0; kc2 < 8; ++kc2) {
#pragma unroll
        for (int u = 0; u < 2; ++u) {
            const int kc  = kc2 * 2 + u;
            const int cur = u, nxt = u ^ 1;
            const int kn  = (kc + 1) & 15;
            const int ks2 = (kc + 2) & 15;

            // 1) prefetch next chunk K/V frags (coalesced 1 KB loads)
#pragma unroll
            for (int s = 0; s < 8; ++s)
                khr[nxt][s] = __builtin_bit_cast(h16x8, khp[(kn * 8 + s) * 64]);
#pragma unroll
            for (int f = 0; f < 8; ++f)
                vr[nxt][f]  = __builtin_bit_cast(h16x8, vp[(kn * 8 + f) * 64]);

            // 2) stage scale(kc+1) VGPR -> LDS
#pragma unroll
            for (int j = 0; j < 4; ++j)
                *(f32x4*)&scb[nxt * 1152 + (j * 8 + (lane >> 3)) * 36 + (lane & 7) * 4] = scv[nxt][j];

            // 3) reload scv[cur] <- scale(kc+2) (coalesced)
#pragma unroll
            for (int j = 0; j < 4; ++j)
                scv[cur][j] = *(const f32x4*)(scale_g + scrow[j] + ks2 * 32);

            // 4) S^T = K Q^T, fp16x2, two parallel chains
            f32x16 Sa, Sb;
#pragma unroll
            for (int r = 0; r < 16; ++r) { Sa[r] = 0.f; Sb[r] = 0.f; }
#pragma unroll
            for (int s = 0; s < 8; ++s) {
                Sa = __builtin_amdgcn_mfma_f32_32x32x16_f16(khr[cur][s], qh[s], Sa, 0, 0, 0);
                Sb = __builtin_amdgcn_mfma_f32_32x32x16_f16(khr[cur][s], ql[s], Sb, 0, 0, 0);
            }
            f32x16 S = Sa + Sb;

            // 5) gather scale(kc) from LDS
            f32x4 scf[4];
#pragma unroll
            for (int G = 0; G < 4; ++G)
                scf[G] = *(const f32x4*)&scb[cur * 1152 + q31 * 36 + (2 * G + h) * 4];

            // 6) online softmax (row q spans lane and lane^32)
            float lt[16];
            float mx = -INFINITY;
#pragma unroll
            for (int r = 0; r < 16; ++r) {
                lt[r] = S[r] * scf[r >> 2][r & 3];
                mx = fmaxf(mx, lt[r]);
            }
            mx = fmaxf(mx, __shfl_xor(mx, 32));
            const float m_new = fmaxf(m_run, mx);
            const float al = fast_exp2((m_run - m_new) * LOG2E);
            m_run = m_new;
            float rs = 0.f;
            float p[16];
#pragma unroll
            for (int r = 0; r < 16; ++r) {
                p[r] = fast_exp2((lt[r] - m_new) * LOG2E);
                rs += p[r];
            }
            rs += __shfl_xor(rs, 32);
            l_run = l_run * al + rs;
#pragma unroll
            for (int t = 0; t < 4; ++t)
#pragma unroll
                for (int r = 0; r < 16; ++r) oacc[t][r] *= al;

            // 7) P C-layout -> B-frag via lane^32 exchange
            unsigned int pa[4], pb[4];
#pragma unroll
            for (int G = 0; G < 4; ++G) {
                pa[G] = __builtin_bit_cast(unsigned int,
                         __builtin_amdgcn_cvt_pkrtz(p[4 * G + 0], p[4 * G + 1]));
                pb[G] = __builtin_bit_cast(unsigned int,
                         __builtin_amdgcn_cvt_pkrtz(p[4 * G + 2], p[4 * G + 3]));
            }
            h16x8 Bf[2];
#pragma unroll
            for (int s2 = 0; s2 < 2; ++s2) {
                const int Gk = 2 * s2 + h;
                unsigned int sa = h ? pa[2 * s2] : pa[2 * s2 + 1];
                unsigned int sb = h ? pb[2 * s2] : pb[2 * s2 + 1];
                unsigned int xa = (unsigned int)__shfl_xor((int)sa, 32);
                unsigned int xb = (unsigned int)__shfl_xor((int)sb, 32);
                u32x4 w;
                w[0] = h ? xa : pa[Gk];
                w[1] = h ? xb : pb[Gk];
                w[2] = h ? pa[Gk] : xa;
                w[3] = h ? pb[Gk] : xb;
                Bf[s2] = __builtin_bit_cast(h16x8, w);
            }

            // 8) O^T += V^T P^T
#pragma unroll
            for (int t = 0; t < 4; ++t)
#pragma unroll
                for (int s2 = 0; s2 < 2; ++s2)
                    oacc[t] = __builtin_amdgcn_mfma_f32_32x32x16_f16(
                                vr[cur][t * 2 + s2], Bf[s2], oacc[t], 0, 0, 0);
        }
    }

    // ---- epilogue: cross-wave m-merge, rescale, O-sum, store ----
    if (h == 0) mstat[wave * 32 + q31] = m_run;
    __syncthreads();                       // all waves done with loop + mstat
    {
        float M = mstat[q31];
#pragma unroll
        for (int w = 1; w < 4; ++w) M = fmaxf(M, mstat[w * 32 + q31]);
        const float al = fast_exp2((m_run - M) * LOG2E);
        if (h == 0) lstat[wave * 32 + q31] = l_run * al;
#pragma unroll
        for (int t = 0; t < 4; ++t)
#pragma unroll
            for (int G = 0; G < 4; ++G) {
                f32x4 v4;
#pragma unroll
                for (int j = 0; j < 4; ++j) v4[j] = oacc[t][4 * G + j] * al;
                *(f32x4*)&oex[wave * 4224 + q31 * 132 + t * 32 + G * 8 + 4 * h] = v4;
            }
    }
    __syncthreads();
    {
        const int qq   = tid >> 3;
        const int dblk = tid & 7;
        const float linv = 1.f / (lstat[qq] + lstat[32 + qq] + lstat[64 + qq] + lstat[96 + qq]);
#pragma unroll
        for (int jj = 0; jj < 2; ++jj) {
            const int d = dblk * 16 + jj * 8;
#pragma unroll
            for (int half = 0; half < 2; ++half) {
                const int dd = d + half * 4;
                f32x4 acc = *(const f32x4*)&oex[qq * 132 + dd];
#pragma unroll
                for (int w = 1; w < 4; ++w) {
                    f32x4 pv = *(const f32x4*)&oex[w * 4224 + qq * 132 + dd];
                    acc[0] += pv[0]; acc[1] += pv[1]; acc[2] += pv[2]; acc[3] += pv[3];
                }
                acc[0] *= linv; acc[1] *= linv; acc[2] *= linv; acc[3] *= linv;
                *(f32x4*)(out + (size_t)(b * 2048 + qt * 32 + qq) * 128 + dd) = acc;
            }
        }
    }
}

extern "C" void kernel_launch(void* const* d_in, const int* in_sizes, int n_in,
                              void* d_out, int out_size, void* d_ws, size_t ws_size,
                              hipStream_t stream) {
    const float* q  = (const float*)d_in[0];
    const float* k  = (const float*)d_in[1];
    const float* v  = (const float*)d_in[2];
    const float* sc = (const float*)d_in[3];
    float* out = (float*)d_out;

    char* ws = (char*)d_ws;
    const size_t MB = 1024 * 1024;
    unsigned short* qhF = (unsigned short*)(ws);
    unsigned short* qlF = (unsigned short*)(ws + 4 * MB);
    unsigned short* khF = (unsigned short*)(ws + 8 * MB);
    unsigned short* vF  = (unsigned short*)(ws + 12 * MB);

    prep_all<<<1536, 256, 0, stream>>>(q, k, v, qhF, qlF, khF, vF);
    flash_fwd<<<512, 256, 0, stream>>>(qhF, qlF, khF, vF, sc, out);
}